// Round 5
// baseline (133.442 us; speedup 1.0000x reference)
//
#include <hip/hip_runtime.h>
#include <hip/hip_bf16.h>
#include <math.h>

#define BB 4
#define SS 2048
#define DD 512
#define HH 8
#define DHH 64
#define MROWS (BB*SS)

constexpr float SCALE  = 0.044194173824159216f;            // 1/sqrt(512)
constexpr float QSCALE = (float)(0.044194173824159216 * 1.4426950408889634); // SCALE*log2(e)
constexpr float LN_EPS = 1e-5f;
constexpr float DEFER_THR = 12.0f;                          // log2-domain (~e^8.3)

typedef __attribute__((ext_vector_type(8))) short bf16x8;
typedef __attribute__((ext_vector_type(4))) float f32x4;

__device__ __forceinline__ ushort f2bf(float f) {
    __hip_bfloat16 h = __float2bfloat16(f);   // RNE; pairs into v_cvt_pk_bf16_f32
    ushort u; __builtin_memcpy(&u, &h, 2);
    return u;
}

__device__ __forceinline__ float exp2_hw(float x) {
#if __has_builtin(__builtin_amdgcn_exp2f)
    return __builtin_amdgcn_exp2f(x);
#else
    return exp2f(x);
#endif
}

__device__ __forceinline__ void gload16(const void* gsrc, void* lds_dst) {
    __builtin_amdgcn_global_load_lds(
        (const __attribute__((address_space(1))) unsigned int*)gsrc,
        (__attribute__((address_space(3))) unsigned int*)lds_dst,
        16, 0, 0);
}

// ---------------------------------------------------------------------------
// Cast/pack: xb = bf16(x); wb = bf16([wq*QS; wk; wv; wo]); biasc = [bq*QS, bk, bv]
// grid 2048, block 256
// ---------------------------------------------------------------------------
__global__ __launch_bounds__(256) void cast_kernel(
    const float* __restrict__ x,
    const float* __restrict__ wq, const float* __restrict__ wk,
    const float* __restrict__ wv, const float* __restrict__ wo,
    const float* __restrict__ bq, const float* __restrict__ bk,
    const float* __restrict__ bv,
    ushort* __restrict__ xb, ushort* __restrict__ wb, float* __restrict__ biasc)
{
    const int gid = blockIdx.x * 256 + threadIdx.x;
    if (gid < 1536) {
        float v = gid < 512 ? bq[gid] * QSCALE
                : gid < 1024 ? bk[gid - 512] : bv[gid - 1024];
        biasc[gid] = v;
    }
    const int NX4 = (MROWS * DD) / 4;     // 1048576
    const int NW4 = (DD * DD) / 4;        // 65536
    const int total = NX4 + 4 * NW4;      // 1310720
    for (int i = gid; i < total; i += gridDim.x * 256) {
        float4 v; ushort4 o;
        if (i < NX4) {
            v = ((const float4*)x)[i];
            o.x = f2bf(v.x); o.y = f2bf(v.y); o.z = f2bf(v.z); o.w = f2bf(v.w);
            ((ushort4*)xb)[i] = o;
        } else {
            int j = i - NX4;
            int which = j >> 16;
            int off = j & 65535;
            const float4* src = which == 0 ? (const float4*)wq
                              : which == 1 ? (const float4*)wk
                              : which == 2 ? (const float4*)wv : (const float4*)wo;
            v = src[off];
            float scl = which == 0 ? QSCALE : 1.0f;
            o.x = f2bf(v.x * scl); o.y = f2bf(v.y * scl);
            o.z = f2bf(v.z * scl); o.w = f2bf(v.w * scl);
            ((ushort4*)wb)[j] = o;
        }
    }
}

// ---------------------------------------------------------------------------
// Shared GEMM-BT machinery: C[128 x 128] = A[128,K] · B[128,K]^T, bf16 MFMA.
// ---------------------------------------------------------------------------
__device__ __forceinline__ void stage_tile(const ushort* __restrict__ g, int k0,
                                           ushort* lbuf, int t)
{
    #pragma unroll
    for (int i = 0; i < 4; ++i) {
        int cc = i * 256 + t;
        int row = cc >> 3, slot = cc & 7;
        gload16(g + row * DD + k0 + ((slot ^ (row & 7)) << 3), lbuf + cc * 8);
    }
}

__device__ __forceinline__ void mma_step(const ushort* Abuf, const ushort* Bbuf,
                                         int wr, int wc, int c, int g,
                                         f32x4 (&acc)[4][4])
{
    bf16x8 af[2][4], bf[2][4];
    #pragma unroll
    for (int kc = 0; kc < 2; ++kc) {
        int sw = ((kc * 4 + g) ^ (c & 7)) << 4;
        #pragma unroll
        for (int mi = 0; mi < 4; ++mi)
            af[kc][mi] = *(const bf16x8*)((const char*)Abuf + (wr*64 + mi*16 + c)*128 + sw);
        #pragma unroll
        for (int ni = 0; ni < 4; ++ni)
            bf[kc][ni] = *(const bf16x8*)((const char*)Bbuf + (wc*64 + ni*16 + c)*128 + sw);
    }
    __builtin_amdgcn_s_setprio(1);
    #pragma unroll
    for (int kc = 0; kc < 2; ++kc)
        #pragma unroll
        for (int mi = 0; mi < 4; ++mi)
            #pragma unroll
            for (int ni = 0; ni < 4; ++ni)
                acc[mi][ni] = __builtin_amdgcn_mfma_f32_16x16x32_bf16(
                    af[kc][mi], bf[kc][ni], acc[mi][ni], 0, 0, 0);
    __builtin_amdgcn_s_setprio(0);
}

// ---------------------------------------------------------------------------
// QKV projection GEMM. grid (12, 64). Epilogue: +bias, bf16, head-split
// [B,H,S,DH] for Q/K; V written TRANSPOSED [B,H,DH,S].
// ---------------------------------------------------------------------------
__global__ __launch_bounds__(256) void qkv_mm(
    const ushort* __restrict__ xb, const ushort* __restrict__ wb,
    const float* __restrict__ biasc,
    ushort* __restrict__ Qb, ushort* __restrict__ Kb, ushort* __restrict__ Vtb)
{
    __shared__ ushort Abuf[128*64];
    __shared__ ushort Bbuf[128*64];
    const int t = threadIdx.x, w = t >> 6, lane = t & 63;
    const int wr = w >> 1, wc = w & 1, c = lane & 15, g = lane >> 4;
    const int nblk = blockIdx.x, mblk = blockIdx.y;

    const ushort* Ag = xb + (size_t)mblk * 128 * DD;
    const ushort* Bg = wb + (size_t)nblk * 128 * DD;

    f32x4 acc[4][4] = {};

    for (int k0 = 0; k0 < DD; k0 += 64) {
        stage_tile(Ag, k0, Abuf, t);
        stage_tile(Bg, k0, Bbuf, t);
        __syncthreads();
        mma_step(Abuf, Bbuf, wr, wc, c, g, acc);
        __syncthreads();
    }

    const int n0 = nblk * 128;
    const int proj = n0 >> 9;
    #pragma unroll
    for (int mi = 0; mi < 4; ++mi) {
        int m = mblk*128 + wr*64 + mi*16 + g*4;
        int bi = m >> 11, s = m & 2047;
        #pragma unroll
        for (int ni = 0; ni < 4; ++ni) {
            int ng = n0 + wc*64 + ni*16 + c;
            float bias = biasc[ng];
            int col = ng & 511, h = col >> 6, d = col & 63;
            if (proj == 2) {
                ushort4 o = { f2bf(acc[mi][ni][0] + bias), f2bf(acc[mi][ni][1] + bias),
                              f2bf(acc[mi][ni][2] + bias), f2bf(acc[mi][ni][3] + bias) };
                *(ushort4*)&Vtb[(((size_t)bi*HH + h)*DHH + d)*SS + s] = o;
            } else {
                ushort* outb = proj == 0 ? Qb : Kb;
                #pragma unroll
                for (int rg = 0; rg < 4; ++rg) {
                    outb[(((size_t)bi*HH + h)*SS + (s + rg))*DHH + d] = f2bf(acc[mi][ni][rg] + bias);
                }
            }
        }
    }
}

// ---------------------------------------------------------------------------
// Output projection GEMM + bias + residual (fp32 out). grid (4, 64).
// ---------------------------------------------------------------------------
__global__ __launch_bounds__(256) void oproj_mm(
    const ushort* __restrict__ ctx, const ushort* __restrict__ wob,
    const float* __restrict__ bo, const float* __restrict__ resid,
    float* __restrict__ out)
{
    __shared__ ushort Abuf[128*64];
    __shared__ ushort Bbuf[128*64];
    const int t = threadIdx.x, w = t >> 6, lane = t & 63;
    const int wr = w >> 1, wc = w & 1, c = lane & 15, g = lane >> 4;
    const int nblk = blockIdx.x, mblk = blockIdx.y;

    const ushort* Ag = ctx + (size_t)mblk * 128 * DD;
    const ushort* Bg = wob + (size_t)nblk * 128 * DD;

    f32x4 acc[4][4] = {};

    for (int k0 = 0; k0 < DD; k0 += 64) {
        stage_tile(Ag, k0, Abuf, t);
        stage_tile(Bg, k0, Bbuf, t);
        __syncthreads();
        mma_step(Abuf, Bbuf, wr, wc, c, g, acc);
        __syncthreads();
    }

    #pragma unroll
    for (int mi = 0; mi < 4; ++mi) {
        int m = mblk*128 + wr*64 + mi*16 + g*4;
        #pragma unroll
        for (int ni = 0; ni < 4; ++ni) {
            int ng = nblk*128 + wc*64 + ni*16 + c;
            float bias = bo[ng];
            #pragma unroll
            for (int rg = 0; rg < 4; ++rg) {
                int mm = m + rg;
                out[(size_t)mm*DD + ng] = acc[mi][ni][rg] + bias + resid[(size_t)mm*DD + ng];
            }
        }
    }
}

// ---------------------------------------------------------------------------
// Flash attention, bf16 MFMA 16x16x32. 2 waves/block (128 thr), 32 q/wave
// (2 q-subtiles of 16 -> K/V LDS frags reused 2x). KVBLK=64, double-buffered
// global_load_lds staging, XCD-contiguous head mapping. grid 1024 x 128 thr.
// ---------------------------------------------------------------------------
__global__ __launch_bounds__(128) void attn_kernel(
    const ushort* __restrict__ Q, const ushort* __restrict__ K,
    const ushort* __restrict__ Vt, ushort* __restrict__ ctx)
{
    __shared__ ushort Ks[2][64*64];    // 16 KB
    __shared__ ushort Vts[2][64*64];   // 16 KB
    __shared__ ushort Ps[2][32*64];    //  8 KB  (per-wave 32q x 64k)

    const int t = threadIdx.x;
    const int w = t >> 6, l = t & 63;
    const int g = l >> 4, c = l & 15;

    // XCD swizzle: hw block i -> XCD i%8; give each XCD contiguous work ids
    // so one head's 32 q-tiles (and its K/V) live on one XCD's L2. 1024%8==0.
    const int id  = blockIdx.x;
    const int swz = (id & 7) * 128 + (id >> 3);
    const int qt = swz & 31;
    const int h  = (swz >> 5) & 7;
    const int b  = swz >> 8;
    const size_t bh = (size_t)b * HH + h;

    // Q fragments for 2 q-subtiles: q = qt*64 + w*32 + qs*16 + c
    const ushort* Qbase = Q + (bh * SS + (size_t)qt*64 + w*32 + c) * DHH;
    bf16x8 qf[2][2];
    #pragma unroll
    for (int qs = 0; qs < 2; ++qs) {
        qf[qs][0] = *(const bf16x8*)&Qbase[qs*16*DHH + g*8];
        qf[qs][1] = *(const bf16x8*)&Qbase[qs*16*DHH + 32 + g*8];
    }

    // staging geometry: thread t covers row r=t>>3 (of 16-row chunk), slot sl
    const int r = t >> 3, sl = t & 7;
    const int swsl = (sl ^ (r & 7)) << 3;     // pre-swizzled global slot (rule #21)
    const ushort* Kbase  = K  + bh * SS * DHH;
    const ushort* Vtbase = Vt + bh * DHH * SS;

#define ATTN_STAGE(kvi, bi_) do {                                          \
        const ushort* kp_ = Kbase  + (size_t)(kvi) * 64 * DHH;             \
        const ushort* vp_ = Vtbase + (kvi) * 64;                           \
        _Pragma("unroll")                                                  \
        for (int i_ = 0; i_ < 4; ++i_) {                                   \
            gload16(kp_ + (16*i_ + r)*DHH + swsl,                          \
                    &Ks[bi_][(16*i_ + r)*64 + sl*8]);                      \
            gload16(vp_ + (size_t)(16*i_ + r)*SS + swsl,                   \
                    &Vts[bi_][(16*i_ + r)*64 + sl*8]);                     \
        }                                                                  \
    } while (0)

    f32x4 acc[4][2] = {};
    float m[2]    = {-INFINITY, -INFINITY};
    float lsum[2] = {0.f, 0.f};

    ATTN_STAGE(0, 0);

    for (int kv = 0; kv < SS/64; ++kv) {
        const int cur = kv & 1;
        __syncthreads();                       // tile kv staged (vmcnt drained)
        if (kv + 1 < SS/64) ATTN_STAGE(kv + 1, cur ^ 1);

        const ushort* Kc = Ks[cur];
        const ushort* Vc = Vts[cur];

        // ---- S^T = K · Q^T : K-frags read once, used for both q-subtiles ----
        f32x4 s[4][2];
        __builtin_amdgcn_s_setprio(1);
        #pragma unroll
        for (int krb = 0; krb < 4; ++krb) {
            int row = krb*16 + c;
            bf16x8 kf0 = *(const bf16x8*)((const char*)Kc + row*128 + ((g       ^ (row & 7)) << 4));
            bf16x8 kf1 = *(const bf16x8*)((const char*)Kc + row*128 + (((4 + g) ^ (row & 7)) << 4));
            #pragma unroll
            for (int qs = 0; qs < 2; ++qs) {
                f32x4 z = {0.f, 0.f, 0.f, 0.f};
                z = __builtin_amdgcn_mfma_f32_16x16x32_bf16(kf0, qf[qs][0], z, 0, 0, 0);
                z = __builtin_amdgcn_mfma_f32_16x16x32_bf16(kf1, qf[qs][1], z, 0, 0, 0);
                s[krb][qs] = z;
            }
        }
        __builtin_amdgcn_s_setprio(0);

        // ---- online softmax (log2 domain), defer-max, per q-subtile ----
        float tm[2];
        #pragma unroll
        for (int qs = 0; qs < 2; ++qs) {
            float a0 = fmaxf(fmaxf(s[0][qs][0], s[0][qs][1]), fmaxf(s[0][qs][2], s[0][qs][3]));
            float a1 = fmaxf(fmaxf(s[1][qs][0], s[1][qs][1]), fmaxf(s[1][qs][2], s[1][qs][3]));
            float a2 = fmaxf(fmaxf(s[2][qs][0], s[2][qs][1]), fmaxf(s[2][qs][2], s[2][qs][3]));
            float a3 = fmaxf(fmaxf(s[3][qs][0], s[3][qs][1]), fmaxf(s[3][qs][2], s[3][qs][3]));
            float tmax = fmaxf(fmaxf(a0, a1), fmaxf(a2, a3));
            tmax = fmaxf(tmax, __shfl_xor(tmax, 16));
            tmax = fmaxf(tmax, __shfl_xor(tmax, 32));
            tm[qs] = tmax;
        }

        if (!__all(tm[0] <= m[0] + DEFER_THR && tm[1] <= m[1] + DEFER_THR)) {
            #pragma unroll
            for (int qs = 0; qs < 2; ++qs) {
                float mnew = fmaxf(m[qs], tm[qs]);
                float corr = exp2_hw(m[qs] - mnew);
                lsum[qs] *= corr;
                #pragma unroll
                for (int db = 0; db < 4; ++db) acc[db][qs] *= corr;
                m[qs] = mnew;
            }
        }

        float p[4][2][4];
        float psum[2] = {0.f, 0.f};
        #pragma unroll
        for (int qs = 0; qs < 2; ++qs) {
            #pragma unroll
            for (int krb = 0; krb < 4; ++krb)
                #pragma unroll
                for (int rg = 0; rg < 4; ++rg) {
                    float e = exp2_hw(s[krb][qs][rg] - m[qs]);
                    p[krb][qs][rg] = e; psum[qs] += e;
                }
            psum[qs] += __shfl_xor(psum[qs], 16);
            psum[qs] += __shfl_xor(psum[qs], 32);
            lsum[qs] += psum[qs];
        }

        // ---- P -> LDS (bf16, [32 q][64 k], swizzled, wave-local) ----
        ushort* Pw = Ps[w];
        #pragma unroll
        for (int qs = 0; qs < 2; ++qs) {
            int prow = qs*16 + c;     // prow&7 == c&7
            #pragma unroll
            for (int krb = 0; krb < 4; ++krb) {
                int k0 = krb*16 + g*4;
                ushort4 pk = { f2bf(p[krb][qs][0]), f2bf(p[krb][qs][1]),
                               f2bf(p[krb][qs][2]), f2bf(p[krb][qs][3]) };
                *(ushort4*)((char*)Pw + prow*128 + ((((k0 >> 3) ^ (c & 7))) << 4) + (k0 & 7)*2) = pk;
            }
        }

        // ---- O^T += V^T · P^T : V-frags read once, used for both q-subtiles ----
        #pragma unroll
        for (int jch = 0; jch < 2; ++jch) {
            bf16x8 pf[2];
            #pragma unroll
            for (int qs = 0; qs < 2; ++qs)
                pf[qs] = *(const bf16x8*)((const char*)Pw + (qs*16 + c)*128 + (((jch*4 + g) ^ (c & 7)) << 4));
            __builtin_amdgcn_s_setprio(1);
            #pragma unroll
            for (int db = 0; db < 4; ++db) {
                int row = db*16 + c;
                bf16x8 vf = *(const bf16x8*)((const char*)Vc + row*128 + (((jch*4 + g) ^ (row & 7)) << 4));
                #pragma unroll
                for (int qs = 0; qs < 2; ++qs)
                    acc[db][qs] = __builtin_amdgcn_mfma_f32_16x16x32_bf16(vf, pf[qs], acc[db][qs], 0, 0, 0);
            }
            __builtin_amdgcn_s_setprio(0);
        }
    }
#undef ATTN_STAGE

    #pragma unroll
    for (int qs = 0; qs < 2; ++qs) {
        const float rl = 1.f / lsum[qs];
        const int qglob = qt*64 + w*32 + qs*16 + c;
        ushort* outp = ctx + ((size_t)b*SS + qglob) * DD + h*DHH;
        #pragma unroll
        for (int db = 0; db < 4; ++db) {
            ushort4 o = { f2bf(acc[db][qs][0]*rl), f2bf(acc[db][qs][1]*rl),
                          f2bf(acc[db][qs][2]*rl), f2bf(acc[db][qs][3]*rl) };
            *(ushort4*)&outp[db*16 + 4*g] = o;
        }
    }
}

// ---------------------------------------------------------------------------
// Row LayerNorm
// ---------------------------------------------------------------------------
__global__ __launch_bounds__(256) void ln_kernel(
    const float* __restrict__ y, const float* __restrict__ gamma,
    const float* __restrict__ beta, float* __restrict__ out)
{
    const int row = blockIdx.x;
    const int t = threadIdx.x;
    const float* yr = y + (size_t)row * DD;

    float2 v = *(const float2*)&yr[t*2];
    float s  = v.x + v.y;
    float sq = v.x*v.x + v.y*v.y;
    #pragma unroll
    for (int off = 1; off < 64; off <<= 1) {
        s  += __shfl_xor(s,  off);
        sq += __shfl_xor(sq, off);
    }
    __shared__ float ss[4], ssq[4];
    int wv = t >> 6;
    if ((t & 63) == 0) { ss[wv] = s; ssq[wv] = sq; }
    __syncthreads();
    s  = ss[0] + ss[1] + ss[2] + ss[3];
    sq = ssq[0] + ssq[1] + ssq[2] + ssq[3];

    float mean = s * (1.0f / DD);
    float var  = sq * (1.0f / DD) - mean * mean;
    float rstd = rsqrtf(var + LN_EPS);

    float2 g  = *(const float2*)&gamma[t*2];
    float2 be = *(const float2*)&beta[t*2];
    float2 o;
    o.x = (v.x - mean) * rstd * g.x + be.x;
    o.y = (v.y - mean) * rstd * g.y + be.y;
    *(float2*)&out[(size_t)row * DD + t*2] = o;
}

// ---------------------------------------------------------------------------
extern "C" void kernel_launch(void* const* d_in, const int* in_sizes, int n_in,
                              void* d_out, int out_size, void* d_ws, size_t ws_size,
                              hipStream_t stream)
{
    const float* x     = (const float*)d_in[0];
    const float* wq    = (const float*)d_in[1];
    const float* bq    = (const float*)d_in[2];
    const float* wk    = (const float*)d_in[3];
    const float* bk    = (const float*)d_in[4];
    const float* wv    = (const float*)d_in[5];
    const float* bv    = (const float*)d_in[6];
    const float* wo    = (const float*)d_in[7];
    const float* bo    = (const float*)d_in[8];
    const float* gamma = (const float*)d_in[9];
    const float* beta  = (const float*)d_in[10];

    char* wsb = (char*)d_ws;
    const size_t MB = 1u << 20;
    ushort* xb    = (ushort*)(wsb + 0*MB);    // 8 MB
    ushort* wb    = (ushort*)(wsb + 8*MB);    // 2 MB
    float*  biasc = (float* )(wsb + 10*MB);   // 6 KB
    ushort* Qb    = (ushort*)(wsb + 11*MB);   // 8 MB
    ushort* Kb    = (ushort*)(wsb + 19*MB);   // 8 MB
    ushort* Vtb   = (ushort*)(wsb + 27*MB);   // 8 MB (transposed V, from qkv_mm)
    ushort* ctxb  = (ushort*)(wsb + 35*MB);   // 8 MB
    float*  ybuf  = (float*)(wsb + 11*MB);    // 16 MB over Qb+Kb (dead after attn)

    cast_kernel<<<2048, 256, 0, stream>>>(x, wq, wk, wv, wo, bq, bk, bv,
                                          xb, wb, biasc);
    {
        dim3 grid(12, 64);
        qkv_mm<<<grid, 256, 0, stream>>>(xb, wb, biasc, Qb, Kb, Vtb);
    }
    {
        attn_kernel<<<1024, 128, 0, stream>>>(Qb, Kb, Vtb, ctxb);
    }
    {
        dim3 grid(4, 64);
        oproj_mm<<<grid, 256, 0, stream>>>(ctxb, wb + 3*DD*DD, bo, x, ybuf);
    }
    ln_kernel<<<MROWS, 256, 0, stream>>>(ybuf, gamma, beta, (float*)d_out);
}